// Round 14
// baseline (827.691 us; speedup 1.0000x reference)
//
#include <hip/hip_runtime.h>
#include <hip/hip_bf16.h>

// RGCN layer: out = relu(x @ W_self^T + b + agg/deg)
// Pipeline v24 (3 dispatches): v23 resubmit + 4-deep batched bucket-resident gather
//   Z[n, 0..1151] = xb[n] @ [W_0|...|W_7|W_self];  out = relu(Zself + b + avg(Z[src,rel]))
//   1. K1 prep+coarse (block ranges): xb = bf16(x) | Wcol | coarse: LDS presort by
//      bucket -> CONTIGUOUS 8KB record chunk + cmat prefix row (no global atomics)
//   2. K2 zgemm (pure): XCD-contiguous (strip,chunk); 16KB W LDS (XOR swizzle),
//      MFMA, Zs transpose, full-line stores
//   3. K3 gather: ONE BLOCK PER BUCKET (512 thr). Reads the bucket's 391 record-runs
//      straight from K1 chunks; records wave-uniform (readfirstlane), 4-deep batched;
//      64 lanes load the 256B Z row; LDS f32 atomics into acc[64][128]; dcnt lane0;
//      epilogue relu(Zself + bias + acc/deg) -> out. No intermediate arrays.

#define D 128
#define RNUM 8
#define KREL (RNUM * D)      // 1024
#define KTOT (KREL + D)      // 1152 — Z row pitch
#define ZCH 64               // zgemm cols per block
#define ZNB 64               // zgemm nodes per block (4 waves x 16)
#define ZSP 72               // Zs LDS pitch in elems

#define BSHIFT 6             // 64 nodes per bucket
#define BRANGE 64
#define CROW   784           // cmat row stride (782 buckets + tail, padded)

typedef short short8 __attribute__((ext_vector_type(8)));
typedef float float4v __attribute__((ext_vector_type(4)));

// fp32 -> bf16 round-nearest-even (bit pattern)
static __device__ __forceinline__ unsigned int f2b(float f) {
    unsigned int u = __float_as_uint(f);
    return (u + 0x7fffu + ((u >> 16) & 1u)) >> 16;
}
static __device__ __forceinline__ float b2f_lo(unsigned int u) {
    return __uint_as_float(u << 16);
}
static __device__ __forceinline__ float b2f_hi(unsigned int u) {
    return __uint_as_float(u & 0xffff0000u);
}

static __device__ __forceinline__ void gl_lds16(const void* g, void* l) {
    __builtin_amdgcn_global_load_lds(
        (const __attribute__((address_space(1))) unsigned int*)g,
        (__attribute__((address_space(3))) unsigned int*)l, 16, 0, 0);
}

// ---------- K1: prep (xb | Wcol) + coarse presorted bucket chunks ----------
__global__ __launch_bounds__(256) void prep_coarse_kernel(
        const float* __restrict__ x,
        const float* __restrict__ W_rel,
        const float* __restrict__ W_self,
        const int* __restrict__ ei, const int* __restrict__ et,
        unsigned short* __restrict__ xb,
        unsigned short* __restrict__ Wcol,
        int* __restrict__ data,        // [nco][2048] block-major presorted records
        int* __restrict__ cmat,        // [nco][CROW] per-block bucket prefix rows
        int Nn, int E, int xb_blocks, int wc_blocks) {
    __shared__ int cnt[CROW];
    __shared__ int ps[256];
    __shared__ int recs[2048];
    const int t = threadIdx.x;

    if (blockIdx.x < (unsigned)xb_blocks) {
        int tt = blockIdx.x * 256 + t;
        int n = tt >> 5;             // 32 threads/row, 4 cols each
        int c = (tt & 31) * 4;
        if (n >= Nn) return;
        float4 v = *(const float4*)(x + (size_t)n * D + c);
        unsigned int p0 = f2b(v.x) | (f2b(v.y) << 16);
        unsigned int p1 = f2b(v.z) | (f2b(v.w) << 16);
        *(uint2*)(xb + (size_t)n * D + c) = make_uint2(p0, p1);
    } else if (blockIdx.x < (unsigned)(xb_blocks + wc_blocks)) {
        int idx = (blockIdx.x - xb_blocks) * 256 + t;
        if (idx >= KTOT * D) return;
        int c = idx >> 7;            // output col 0..1151
        int k = idx & 127;           // input dim
        float v = (c < KREL)
            ? W_rel[(size_t)((c >> 7) * D + k) * D + (c & 127)]   // W_rel[r][k][o]
            : W_self[(size_t)(c - KREL) * D + k];                 // W_self[o][k]
        Wcol[idx] = (unsigned short)f2b(v);
    } else {
        // ---- coarse: count -> LDS scan -> LDS scatter -> contiguous write ----
        int blk = blockIdx.x - xb_blocks - wc_blocks;
        for (int i = t; i < CROW; i += 256) cnt[i] = 0;
        __syncthreads();

        int rec[8], rb[8], rk[8];
        int e0 = blk * 2048;
#pragma unroll
        for (int j = 0; j < 8; ++j) {
            int e = e0 + j * 256 + t;
            bool ok = e < E;
            int s = ok ? ei[e] : 0;
            int d = ok ? ei[E + e] : 0;
            int r = ok ? et[e] : 0;
            rec[j] = (s * KTOT + r * D) | ((d & (BRANGE - 1)) << 26);
            rb[j] = ok ? (d >> BSHIFT) : -1;
            rk[j] = ok ? atomicAdd(&cnt[d >> BSHIFT], 1) : 0;
        }
        __syncthreads();

        // exclusive scan of cnt[784]: 4 entries/thread + Hillis-Steele on partials
        int s4 = 0;
#pragma unroll
        for (int i = 0; i < 4; ++i) {
            int idx = t * 4 + i;
            if (idx < CROW) s4 += cnt[idx];
        }
        ps[t] = s4;
        __syncthreads();
        for (int off = 1; off < 256; off <<= 1) {
            int v = (t >= off) ? ps[t - off] : 0;
            __syncthreads();
            ps[t] += v;
            __syncthreads();
        }
        int ex = t ? ps[t - 1] : 0;
#pragma unroll
        for (int i = 0; i < 4; ++i) {
            int idx = t * 4 + i;
            if (idx < CROW) {
                int c = cnt[idx];
                cnt[idx] = ex;
                cmat[(size_t)blk * CROW + idx] = ex;   // coalesced prefix row
                ex += c;
            }
        }
        __syncthreads();

        // scatter records into bucket order in LDS
#pragma unroll
        for (int j = 0; j < 8; ++j)
            if (rb[j] >= 0) recs[cnt[rb[j]] + rk[j]] = rec[j];
        __syncthreads();

        // contiguous full-line write: 8 KB per block
        int4* dsrc = (int4*)recs;
        int4* ddst = (int4*)(data + (size_t)blk * 2048);
        ddst[t * 2]     = dsrc[t * 2];
        ddst[t * 2 + 1] = dsrc[t * 2 + 1];
    }
}

// ---------- K2: zgemm (pure), XCD-contiguous strip mapping ----------
__global__ __launch_bounds__(256) void zgemm_kernel(
        const unsigned short* __restrict__ xb,    // [npad][128]
        const unsigned short* __restrict__ Wcol,  // [1152][128]
        unsigned short* __restrict__ Z,           // [npad][1152]
        int nstrip, int spx) {
    __shared__ unsigned short Ws[ZCH * 128];      // 16384 B
    __shared__ unsigned short Zs[ZNB * ZSP];      //  9216 B

    const int xcd = blockIdx.x & 7;
    const int i0  = blockIdx.x >> 3;
    const int strip = xcd * spx + i0 / 18;
    const int chunk = i0 % 18;
    if (strip >= nstrip) return;               // pad strips (uniform)

    const int tid  = threadIdx.x;
    const int lane = tid & 63;
    const int w    = tid >> 6;       // 0..3
    const int l16  = lane & 15;
    const int q    = lane >> 4;      // 0..3
    const int c0   = chunk * ZCH;
    const int n0   = strip * ZNB;
    const int n    = n0 + w * 16 + l16;    // this lane's node

    // xb B-frags: K=128 = 4 windows of 32, loaded ONCE
    short8 xq[4];
#pragma unroll
    for (int kw = 0; kw < 4; ++kw)
        xq[kw] = *(const short8*)(xb + (size_t)n * D + kw * 32 + q * 8);

    // stage W chunk: 1024 16B pieces; LDS slot s holds piece (s&15)^(c&15)
#pragma unroll
    for (int i = 0; i < 4; ++i) {
        int s = i * 256 + w * 64 + lane;
        int c = s >> 4;
        int p = (s & 15) ^ (c & 15);
        gl_lds16(Wcol + (size_t)(c0 + c) * D + p * 8,
                 &Ws[(size_t)(i * 256 + w * 64) * 8]);
    }
    __syncthreads();     // drains vmcnt (xq + stage)

    float4v acc[4] = {};
#pragma unroll
    for (int cg = 0; cg < 4; ++cg) {
#pragma unroll
        for (int kw = 0; kw < 4; ++kw) {
            // A-frag: row c = cg*16+l16 (c&15 == l16), logical piece kw*4+q
            short8 a = *(const short8*)(
                &Ws[(((cg * 16 + l16) << 4) + ((kw * 4 + q) ^ l16)) * 8]);
            acc[cg] = __builtin_amdgcn_mfma_f32_16x16x32_bf16(
                a, xq[kw], acc[cg], 0, 0, 0);
        }
    }

    // park accs in LDS (node row = w*16+l16, col = cg*16 + q*4)
#pragma unroll
    for (int cg = 0; cg < 4; ++cg) {
        unsigned int lo = f2b(acc[cg][0]) | (f2b(acc[cg][1]) << 16);
        unsigned int hi = f2b(acc[cg][2]) | (f2b(acc[cg][3]) << 16);
        *(uint2*)(&Zs[(w * 16 + l16) * ZSP + cg * 16 + q * 4]) = make_uint2(lo, hi);
    }
    __syncthreads();

    // full-line stores: thread t -> node row t>>2, 16B piece t&3 (+64B 2nd half)
    {
        int row = tid >> 2;
        int pc  = (tid & 3) * 8;     // elem offset 0,8,16,24
        short8 z0 = *(const short8*)(&Zs[row * ZSP + pc]);
        short8 z1 = *(const short8*)(&Zs[row * ZSP + pc + 32]);
        unsigned short* dst = Z + (size_t)(n0 + row) * KTOT + c0;
        *(short8*)(dst + pc)      = z0;
        *(short8*)(dst + pc + 32) = z1;
    }
}

// ---------- K3: bucket-resident gather — LDS f32 accumulate, direct out ----------
__global__ __launch_bounds__(512) void gather_kernel(
        const unsigned short* __restrict__ Z,     // [npad][1152]
        const int* __restrict__ data,             // [nco][2048] presorted chunks
        const int* __restrict__ cmat,             // [nco][CROW]
        const float* __restrict__ bias,
        float* __restrict__ out,
        int Nn, int nco) {
    __shared__ float acc[BRANGE * D];     // 32768 B
    __shared__ int dcnt[BRANGE];          //   256 B
    __shared__ int rs[400], re[400];      //  3200 B  (nco = 391 runs)

    const int b    = blockIdx.x;
    const int t    = threadIdx.x;
    const int lane = t & 63;
    const int wid  = t >> 6;              // 0..7
    const int laneoff = lane * 2;

    for (int i = t; i < BRANGE * D; i += 512) acc[i] = 0.0f;
    if (t < BRANGE) dcnt[t] = 0;
    for (int i = t; i < nco; i += 512) {
        rs[i] = i * 2048 + cmat[(size_t)i * CROW + b];
        re[i] = i * 2048 + cmat[(size_t)i * CROW + b + 1];
    }
    __syncthreads();

    // each wave walks its share of runs; records wave-uniform via readfirstlane;
    // 4-deep batches pipeline the scalar-load -> Z-row-load chain
    for (int i = wid; i < nco; i += 8) {
        int ks = __builtin_amdgcn_readfirstlane(rs[i]);
        int ke = __builtin_amdgcn_readfirstlane(re[i]);
        int k = ks;
        for (; k + 4 <= ke; k += 4) {
            int rc[4];
#pragma unroll
            for (int j = 0; j < 4; ++j)
                rc[j] = __builtin_amdgcn_readfirstlane(data[k + j]);   // SGPR
            unsigned int u[4];
#pragma unroll
            for (int j = 0; j < 4; ++j)
                u[j] = *(const unsigned int*)(
                    Z + (size_t)(rc[j] & 0x03FFFFFF) + laneoff);
#pragma unroll
            for (int j = 0; j < 4; ++j) {
                int node = ((unsigned)rc[j]) >> 26;
                if (lane == 0) atomicAdd(&dcnt[node], 1);
                atomicAdd(&acc[node * D + laneoff],     b2f_lo(u[j]));
                atomicAdd(&acc[node * D + laneoff + 1], b2f_hi(u[j]));
            }
        }
        for (; k < ke; ++k) {
            int rc = __builtin_amdgcn_readfirstlane(data[k]);
            int node = ((unsigned)rc) >> 26;
            unsigned int u = *(const unsigned int*)(
                Z + (size_t)(rc & 0x03FFFFFF) + laneoff);
            if (lane == 0) atomicAdd(&dcnt[node], 1);
            atomicAdd(&acc[node * D + laneoff],     b2f_lo(u));
            atomicAdd(&acc[node * D + laneoff + 1], b2f_hi(u));
        }
    }
    __syncthreads();

    // epilogue: out = relu(Z_self + bias + acc/deg), coalesced
    for (int i = t; i < BRANGE * D; i += 512) {
        int node = i >> 7;
        int col  = i & 127;
        int gn = b * BRANGE + node;
        if (gn < Nn) {
            float inv = 1.0f / fmaxf((float)dcnt[node], 1.0f);
            unsigned int zsv = Z[(size_t)gn * KTOT + KREL + col];
            float zself = __uint_as_float(zsv << 16);
            out[(size_t)gn * D + col] = fmaxf(zself + bias[col] + acc[i] * inv, 0.0f);
        }
    }
}

extern "C" void kernel_launch(void* const* d_in, const int* in_sizes, int n_in,
                              void* d_out, int out_size, void* d_ws, size_t ws_size,
                              hipStream_t stream) {
    const float* x      = (const float*)d_in[0];
    const float* W_rel  = (const float*)d_in[1];
    const float* W_self = (const float*)d_in[2];
    const float* W_bias = (const float*)d_in[3];
    const int*   ei     = (const int*)d_in[4];
    const int*   et     = (const int*)d_in[5];

    const int Nn = in_sizes[0] / D;       // 50000
    const int E  = in_sizes[4] / 2;       // 800000
    const int npad = ((Nn + ZNB - 1) / ZNB) * ZNB;        // 50048
    const int nstrip = npad / ZNB;                        // 782
    const int spx  = (nstrip + 7) / 8;                    // 98 strips per XCD
    const int zg   = spx * 8 * 18;                        // 14112 zgemm blocks
    const int nbkt = (Nn + BRANGE - 1) >> BSHIFT;         // 782
    const int nco  = (E + 2047) / 2048;                   // 391 coarse blocks

    // ---- workspace layout (256B aligned chunks) ----
    char* p = (char*)d_ws;
    auto take = [&](size_t bytes) { char* q = p; p += (bytes + 255) & ~(size_t)255; return q; };
    unsigned short* Z    = (unsigned short*)take((size_t)npad * KTOT * sizeof(unsigned short));
    unsigned short* xb   = (unsigned short*)take((size_t)npad * D * sizeof(unsigned short));
    unsigned short* Wcol = (unsigned short*)take((size_t)KTOT * D * sizeof(unsigned short));
    int* data    = (int*)take((size_t)nco * 2048 * sizeof(int));   // presorted chunks
    int* cmat    = (int*)take((size_t)nco * CROW * sizeof(int));   // prefix rows

    const int xb_blocks = (Nn * 32 + 255) / 256;
    const int wc_blocks = (KTOT * D + 255) / 256;

    prep_coarse_kernel<<<xb_blocks + wc_blocks + nco, 256, 0, stream>>>(
        x, W_rel, W_self, ei, et, xb, Wcol, data, cmat, Nn, E, xb_blocks, wc_blocks);
    zgemm_kernel<<<zg, 256, 0, stream>>>(xb, Wcol, Z, nstrip, spx);
    gather_kernel<<<nbkt, 512, 0, stream>>>(Z, data, cmat, W_bias,
                                            (float*)d_out, Nn, nco);
}